// Round 3
// baseline (577.254 us; speedup 1.0000x reference)
//
#include <hip/hip_runtime.h>
#include <math.h>

#define B 32
#define C 1536
#define T 2000
#define NBT (B * T)        // 64000
#define CSPLIT 16
#define CCH (C / CSPLIT)   // 96
#define T4 (T / 4)         // 500
#define BN_EPS 1e-5f
#define K2_BLOCKS 250      // 250 * 256 == 64000 exactly

using f4 = __attribute__((ext_vector_type(4))) float;

// -------- ws layout (floats) --------
// a_part : [CSPLIT][NBT]   (1,024,000)
// a      : [NBT]           (64,000)
// attn   : [NBT]           (64,000)
// psums  : [2*K2_BLOCKS]   (500)

// Kernel 1: partial 1x1 conv over a 96-channel chunk. 1024 blocks.
// Normal (caching) loads on purpose: these reads populate L3 for k4's
// second pass. Dispatch order ck=0..15 -> ck=15 is the most recent
// resident chunk when k1 finishes.
__global__ __launch_bounds__(256) void k1_conv(const float* __restrict__ x,
                                               const float* __restrict__ w,
                                               float* __restrict__ a_part) {
  const int t4 = blockIdx.x * 256 + threadIdx.x;   // float4 index in [0,500)
  const int b  = blockIdx.y;
  const int ck = blockIdx.z;
  if (t4 >= T4) return;
  const int c0 = ck * CCH;
  const f4* xp = reinterpret_cast<const f4*>(x) + ((size_t)b * C + c0) * T4;
  f4 acc = (f4)0.f;
#pragma unroll 8
  for (int j = 0; j < CCH; ++j) {
    const float wc = w[c0 + j];            // wave-uniform -> scalar load
    const f4 v = xp[(size_t)j * T4 + t4];
    acc += v * wc;
  }
  reinterpret_cast<f4*>(a_part + (size_t)ck * NBT + b * T)[t4] = acc;
}

// Kernel 2: a[b,t] = sum of 16 partials + conv_b; block tree-reduce of
// sum / sumsq -> 250 partial pairs (deterministic, no atomics).
__global__ __launch_bounds__(256) void k2_reduce(const float* __restrict__ a_part,
                                                 const float* __restrict__ conv_b,
                                                 float* __restrict__ a,
                                                 float* __restrict__ psums) {
  const int i = blockIdx.x * 256 + threadIdx.x;    // < 64000 exactly
  float v = conv_b[0];
#pragma unroll
  for (int k = 0; k < CSPLIT; ++k) v += a_part[(size_t)k * NBT + i];
  a[i] = v;

  float s1 = v, s2 = v * v;
#pragma unroll
  for (int off = 32; off; off >>= 1) {
    s1 += __shfl_xor(s1, off);
    s2 += __shfl_xor(s2, off);
  }
  __shared__ float ls1[4], ls2[4];
  const int wid = threadIdx.x >> 6, lane = threadIdx.x & 63;
  if (lane == 0) { ls1[wid] = s1; ls2[wid] = s2; }
  __syncthreads();
  if (threadIdx.x == 0) {
    psums[blockIdx.x]             = ls1[0] + ls1[1] + ls1[2] + ls1[3];
    psums[K2_BLOCKS + blockIdx.x] = ls2[0] + ls2[1] + ls2[2] + ls2[3];
  }
}

// Kernel 3: one block per batch row (1024 thr -> 2 transcendental iters).
// Redundantly reduce the 250 partial pairs -> mu/var, then BN + tanh +
// softmax over time in LDS.
__global__ __launch_bounds__(1024) void k3_softmax(const float* __restrict__ a,
                                                   const float* __restrict__ psums,
                                                   const float* __restrict__ gamma,
                                                   const float* __restrict__ beta,
                                                   float* __restrict__ attn) {
  __shared__ float sv[T];
  __shared__ float r1[16], r2[16], r3[16], r4[16];
  const int tid = threadIdx.x;
  const int wid = tid >> 6, lane = tid & 63;

  // ---- global BN stats ----
  float s1 = 0.f, s2 = 0.f;
  if (tid < K2_BLOCKS) { s1 = psums[tid]; s2 = psums[K2_BLOCKS + tid]; }
#pragma unroll
  for (int off = 32; off; off >>= 1) {
    s1 += __shfl_xor(s1, off);
    s2 += __shfl_xor(s2, off);
  }
  if (lane == 0) { r1[wid] = s1; r2[wid] = s2; }
  __syncthreads();
  float tot1 = 0.f, tot2 = 0.f;
#pragma unroll
  for (int k = 0; k < 16; ++k) { tot1 += r1[k]; tot2 += r2[k]; }
  const float mu  = tot1 / (float)NBT;
  const float var = tot2 / (float)NBT - mu * mu;   // biased var
  const float rs  = 1.0f / sqrtf(var + BN_EPS);
  const float g = gamma[0], be = beta[0];

  // ---- tanh(BN(a)) + row max ----
  const int b = blockIdx.x;
  const float* ab = a + b * T;
  float lmax = -1e30f;
  for (int t = tid; t < T; t += 1024) {
    const float v = tanhf((ab[t] - mu) * rs * g + be);
    sv[t] = v;
    lmax = fmaxf(lmax, v);
  }
#pragma unroll
  for (int off = 32; off; off >>= 1) lmax = fmaxf(lmax, __shfl_xor(lmax, off));
  if (lane == 0) r3[wid] = lmax;
  __syncthreads();
  float m = -1e30f;
#pragma unroll
  for (int k = 0; k < 16; ++k) m = fmaxf(m, r3[k]);

  // ---- exp + row sum ----
  float lsum = 0.f;
  for (int t = tid; t < T; t += 1024) {
    const float p = expf(sv[t] - m);
    sv[t] = p;
    lsum += p;
  }
#pragma unroll
  for (int off = 32; off; off >>= 1) lsum += __shfl_xor(lsum, off);
  if (lane == 0) r4[wid] = lsum;
  __syncthreads();
  float tot = 0.f;
#pragma unroll
  for (int k = 0; k < 16; ++k) tot += r4[k];
  const float inv = 1.0f / tot;

  for (int t = tid; t < T; t += 1024) attn[b * T + t] = sv[t] * inv;
}

// Kernel 4: one wave per (b,c) row, fully unrolled 16 loads up front.
// Row order REVERSED at c-chunk granularity to mirror k1's stream recency:
// ck=15 (most recently resident in L3) is read first, ck=0 last. x reads
// are nontemporal so k4 doesn't evict the still-resident chunks it will
// read next; attn reads are caching (4 MB, reused by all c).
__global__ __launch_bounds__(256) void k4_pool(const float* __restrict__ x,
                                               const float* __restrict__ attn,
                                               float* __restrict__ out) {
  const int wid  = threadIdx.x >> 6;
  const int lane = threadIdx.x & 63;
  // group decode: ck descending, then b, then 4-row group within chunk
  const int g      = blockIdx.x;                 // [0, 12288)
  const int ck_rev = g / (B * (CCH / 4));        // /768 -> [0,16)
  const int rem    = g - ck_rev * (B * (CCH / 4));
  const int b      = rem / (CCH / 4);
  const int j      = rem - b * (CCH / 4);
  const int c      = (CSPLIT - 1 - ck_rev) * CCH + j * 4 + wid;
  const int row    = b * C + c;

  const f4* xr = reinterpret_cast<const f4*>(x)    + (size_t)row * T4;
  const f4* ar = reinterpret_cast<const f4*>(attn) + (size_t)b   * T4;

  f4 xv[8], av[8];
#pragma unroll
  for (int jj = 0; jj < 7; ++jj) {
    xv[jj] = __builtin_nontemporal_load(xr + jj * 64 + lane);
    av[jj] = ar[jj * 64 + lane];
  }
  if (lane < 52) {   // 500 = 7*64 + 52
    xv[7] = __builtin_nontemporal_load(xr + 448 + lane);
    av[7] = ar[448 + lane];
  } else {
    xv[7] = (f4)0.f;
    av[7] = (f4)0.f;
  }

  float sxa = 0.f, sx2a = 0.f;
#pragma unroll
  for (int jj = 0; jj < 8; ++jj) {
    const f4 xa = xv[jj] * av[jj];
    sxa  += xa.x + xa.y + xa.z + xa.w;
    const f4 x2a = xv[jj] * xa;
    sx2a += x2a.x + x2a.y + x2a.z + x2a.w;
  }
#pragma unroll
  for (int off = 32; off; off >>= 1) {
    sxa  += __shfl_xor(sxa, off);
    sx2a += __shfl_xor(sx2a, off);
  }
  if (lane == 0) {
    const float mean = sxa;
    out[(size_t)b * 2 * C + c]     = mean;
    out[(size_t)b * 2 * C + C + c] = sqrtf(fmaxf(sx2a - mean * mean, 1e-10f));
  }
}

extern "C" void kernel_launch(void* const* d_in, const int* in_sizes, int n_in,
                              void* d_out, int out_size, void* d_ws, size_t ws_size,
                              hipStream_t stream) {
  const float* x      = (const float*)d_in[0];
  const float* conv_w = (const float*)d_in[1];
  const float* conv_b = (const float*)d_in[2];
  const float* gamma  = (const float*)d_in[3];
  const float* beta   = (const float*)d_in[4];
  float* out = (float*)d_out;

  float* ws     = (float*)d_ws;
  float* a_part = ws;                                  // CSPLIT*NBT
  float* a      = a_part + (size_t)CSPLIT * NBT;       // NBT
  float* attn   = a + NBT;                             // NBT
  float* psums  = attn + NBT;                          // 2*K2_BLOCKS

  dim3 g1((T4 + 255) / 256, B, CSPLIT);                // (2, 32, 16)
  k1_conv<<<g1, 256, 0, stream>>>(x, conv_w, a_part);
  k2_reduce<<<K2_BLOCKS, 256, 0, stream>>>(a_part, conv_b, a, psums);
  k3_softmax<<<B, 1024, 0, stream>>>(a, psums, gamma, beta, attn);
  k4_pool<<<(B * C) / 4, 256, 0, stream>>>(x, attn, out);
}